// Round 8
// baseline (220.639 us; speedup 1.0000x reference)
//
#include <hip/hip_runtime.h>
#include <hip/hip_bf16.h>

// Problem constants
#define HB 2
#define HS 2048
#define HH 16
#define HD 64
#define HIDN 1024
#define MROWS 4096   // B*S

typedef __attribute__((ext_vector_type(8))) short s16x8;   // 8 bf16 (4 VGPRs)
typedef __attribute__((ext_vector_type(4))) float f32x4;   // MFMA accumulator
typedef unsigned short u16;

__device__ inline u16 f2bf(float f) {
  union { __hip_bfloat16 h; u16 u; } cvt;
  cvt.h = __float2bfloat16(f);
  return cvt.u;
}

// async global->LDS DMA, 16B per lane. lds base must be wave-uniform;
// lane i lands at base + i*16B. global addr is per-lane.
__device__ __forceinline__ void gload16(const u16* g, u16* l) {
  __builtin_amdgcn_global_load_lds((const __attribute__((address_space(1))) void*)g,
                                   (__attribute__((address_space(3))) void*)l, 16, 0, 0);
}

// ---------------- K0a: fp32 -> bf16 convert (hidden_states) ----------------
__global__ __launch_bounds__(256) void k_cvt(const float* __restrict__ in, u16* __restrict__ out, int n) {
  int i = (blockIdx.x * 256 + threadIdx.x) * 4;
  if (i >= n) return;
  float4 a = *(const float4*)(in + i);
  ushort4 r;
  r.x = f2bf(a.x); r.y = f2bf(a.y); r.z = f2bf(a.z); r.w = f2bf(a.w);
  *(ushort4*)(out + i) = r;
}

// ---------------- K0b: weight transpose fp32[K][C] -> bf16[C][K] -----------
__global__ __launch_bounds__(256) void k_transpose(const float* __restrict__ W0, const float* __restrict__ W1,
                                                   const float* __restrict__ W2, const float* __restrict__ W3,
                                                   u16* __restrict__ out) {
  const float* W = (blockIdx.z == 0) ? W0 : (blockIdx.z == 1) ? W1 : (blockIdx.z == 2) ? W2 : W3;
  u16* O = out + (size_t)blockIdx.z * HIDN * HIDN;
  __shared__ float tile[64][65];
  int k0 = blockIdx.y * 64, c0 = blockIdx.x * 64;
  #pragma unroll
  for (int i = 0; i < 16; ++i) {
    int id = threadIdx.x + i * 256;
    int r = id >> 6, c = id & 63;
    tile[r][c] = W[(size_t)(k0 + r) * HIDN + c0 + c];
  }
  __syncthreads();
  #pragma unroll
  for (int i = 0; i < 16; ++i) {
    int id = threadIdx.x + i * 256;
    int r = id >> 6, c = id & 63;
    O[(size_t)(c0 + r) * HIDN + k0 + c] = f2bf(tile[c][r]);
  }
}

// ---------------- K1: QKV GEMM + info add + RoPE epilogue -------------------
#define BM 128
#define BN 128
#define BK 64
#define LDK 72   // padded stride for k_attn P tiles (16B-aligned rows)

__global__ __launch_bounds__(256) void k_qkv(const u16* __restrict__ X, const u16* __restrict__ Wt,
                                             const float* __restrict__ info,
                                             u16* __restrict__ Qb, u16* __restrict__ Kb, u16* __restrict__ Vt) {
  __shared__ __align__(16) u16 smem[128 * 136];
  const int z = blockIdx.z;
  const u16* Bt = Wt + (size_t)z * HIDN * HIDN;
  const int tid = threadIdx.x;
  const int lane = tid & 63, wave = tid >> 6;
  const int wr = wave >> 1, wc = wave & 1;     // 2x2 waves, each owns 64x64
  const int lg = lane >> 4, li = lane & 15;
  const int bm0 = blockIdx.y * BM, bn0 = blockIdx.x * BN;

  const int srow = lane >> 3;          // 0..7 row within 1KB chunk
  const int scol = (lane & 7) * 8;     // k-col element within row

  f32x4 acc[4][4];
  #pragma unroll
  for (int m = 0; m < 4; ++m)
    #pragma unroll
    for (int n = 0; n < 4; ++n) acc[m][n] = (f32x4){0.f, 0.f, 0.f, 0.f};

  for (int k0 = 0; k0 < HIDN; k0 += BK) {
    __syncthreads();
    #pragma unroll
    for (int c = 0; c < 4; ++c) {
      const int ci = wave * 4 + c;
      const int row = ci * 8 + srow;
      gload16(X  + (size_t)(bm0 + row) * HIDN + k0 + scol, &smem[ci * 512]);
      gload16(Bt + (size_t)(bn0 + row) * HIDN + k0 + scol, &smem[8192 + ci * 512]);
    }
    __syncthreads();
    #pragma unroll
    for (int kk = 0; kk < 2; ++kk) {
      s16x8 af[4], bfr[4];
      #pragma unroll
      for (int m = 0; m < 4; ++m) af[m]  = *(const s16x8*)(&smem[(wr * 64 + m * 16 + li) * 64 + kk * 32 + lg * 8]);
      #pragma unroll
      for (int n = 0; n < 4; ++n) bfr[n] = *(const s16x8*)(&smem[8192 + (wc * 64 + n * 16 + li) * 64 + kk * 32 + lg * 8]);
      __builtin_amdgcn_s_setprio(1);
      #pragma unroll
      for (int m = 0; m < 4; ++m)
        #pragma unroll
        for (int n = 0; n < 4; ++n)
          acc[m][n] = __builtin_amdgcn_mfma_f32_16x16x32_bf16(af[m], bfr[n], acc[m][n], 0, 0, 0);
      __builtin_amdgcn_s_setprio(0);
    }
  }

  if (z < 2) {
    u16* dst = (z == 0) ? Qb : Kb;
    #pragma unroll
    for (int m = 0; m < 4; ++m) {
      #pragma unroll
      for (int r = 0; r < 4; ++r) {
        int t = bm0 + wr * 64 + m * 16 + lg * 4 + r;   // global token row
        int b = t >> 11, s = t & (HS - 1);
        #pragma unroll
        for (int n = 0; n < 2; ++n) {                  // rope pairs: frag n with frag n+2
          int c1 = bn0 + wc * 64 + n * 16 + li;        // col for d1 < 32
          float v1 = acc[m][n][r]     + info[(size_t)t * HIDN + c1];
          float v2 = acc[m][n + 2][r] + info[(size_t)t * HIDN + c1 + 32];
          int j = n * 16 + li;                          // freq index 0..31
          float invf = exp2f(-0.41524101186092030f * (float)j);  // 10000^(-j/32)
          float ang = (float)s * invf;
          float sn, cs;
          __sincosf(ang, &sn, &cs);
          float o1 = v1 * cs - v2 * sn;
          float o2 = v2 * cs + v1 * sn;
          if (z == 0) { o1 *= 0.18033688011f; o2 *= 0.18033688011f; } // 1/8 * log2(e)
          int h = c1 >> 6, d1 = c1 & 63;
          size_t base = ((size_t)(b * HH + h) * HS + s) * HD;
          dst[base + d1]      = f2bf(o1);
          dst[base + d1 + 32] = f2bf(o2);
        }
      }
    }
  } else {
    // V: transpose 128x128 block via LDS, then coalesced 16B stores to [B][H][D][S]
    __syncthreads();
    #pragma unroll
    for (int m = 0; m < 4; ++m)
      #pragma unroll
      for (int n = 0; n < 4; ++n)
        #pragma unroll
        for (int r = 0; r < 4; ++r) {
          int cl = wc * 64 + n * 16 + li;
          int ml = wr * 64 + m * 16 + lg * 4 + r;
          smem[cl * 136 + ml] = f2bf(acc[m][n][r]);
        }
    __syncthreads();
    const int b = bm0 >> 11, s0 = bm0 & (HS - 1);
    #pragma unroll
    for (int p = 0; p < 8; ++p) {
      int id = tid + p * 256;
      int cl = id >> 4, m8 = (id & 15) * 8;
      int c = bn0 + cl;
      int h = c >> 6, d = c & 63;
      s16x8 v = *(const s16x8*)(&smem[cl * 136 + m8]);
      *(s16x8*)(&Vt[((size_t)(b * HH + h) * HD + d) * HS + s0 + m8]) = v;
    }
  }
}

// ---------------- K2: causal flash attention (barrier-free, L2-direct) ------
// K/V per head (256KB each) are L2-resident (all blocks of a bh map to one
// XCD: bidx%8==bh%8). So: NO K/V LDS staging, NO __syncthreads in the loop —
// each wave reads its MFMA fragments straight from global (L2 hit) and runs
// fully independently. Only LDS use is the wave-private P roundtrip.
// grid 1024: bh=bidx&31, j=31-(bidx>>5) (largest-work first, queue balance).
// No-max softmax: scores in exp2 domain, P = exp2(S-8), division cancels 2^-8.
__global__ __launch_bounds__(256, 4) void k_attn(const u16* __restrict__ Qb, const u16* __restrict__ Kb,
                                                 const u16* __restrict__ Vt, u16* __restrict__ attnOut) {
  __shared__ u16 Ps[4][16 * LDK];   // per-wave P tile: [qrow][key]
  const int bidx = blockIdx.x;
  const int bh = bidx & 31;
  const int j  = 31 - (bidx >> 5);
  const int q0 = j * 64;
  const int ntiles = j + 1;

  const u16* Qh = Qb + (size_t)bh * HS * HD;
  const u16* Kh = Kb + (size_t)bh * HS * HD;
  const u16* Vh = Vt + (size_t)bh * HD * HS;
  const int tid = threadIdx.x;
  const int lane = tid & 63, w = tid >> 6;
  const int lg = lane >> 4, li = lane & 15;
  const int b = bh >> 4, h = bh & 15;

  // Q fragments in registers (Q pre-scaled by 0.125*log2e)
  s16x8 qf[2];
  #pragma unroll
  for (int kk = 0; kk < 2; ++kk)
    qf[kk] = *(const s16x8*)(Qh + (size_t)(q0 + w * 16 + li) * HD + kk * 32 + lg * 8);

  // per-lane fragment base pointers (advance by 64 keys per tile)
  const u16* kptr = Kh + (size_t)li * HD + lg * 8;        // + n*16*HD + kk*32 + t*64*HD
  const u16* vptr = Vh + (size_t)li * HS + lg * 8;        // + n*16*HS + kk*32 + t*64

  f32x4 o[4];
  #pragma unroll
  for (int n = 0; n < 4; ++n) o[n] = (f32x4){0.f, 0.f, 0.f, 0.f};
  float lrow = 0.f;

  for (int t = 0; t < ntiles; ++t) {
    const int kv0 = t * 64;

    // S^T = K @ Q^T : lane li owns q-row (q0+w*16+li), keys n*16+lg*4+r
    // K fragments straight from L2: row kv0+n*16+li, d-offset kk*32+lg*8
    f32x4 sc[4];
    #pragma unroll
    for (int n = 0; n < 4; ++n) sc[n] = (f32x4){0.f, 0.f, 0.f, 0.f};
    {
      s16x8 kf0[4], kf1[4];
      #pragma unroll
      for (int n = 0; n < 4; ++n) {
        const u16* kp = kptr + (size_t)(kv0 + n * 16) * HD;
        kf0[n] = *(const s16x8*)(kp);
        kf1[n] = *(const s16x8*)(kp + 32);
      }
      __builtin_amdgcn_s_setprio(1);
      #pragma unroll
      for (int n = 0; n < 4; ++n) {
        sc[n] = __builtin_amdgcn_mfma_f32_16x16x32_bf16(kf0[n], qf[0], sc[n], 0, 0, 0);
        sc[n] = __builtin_amdgcn_mfma_f32_16x16x32_bf16(kf1[n], qf[1], sc[n], 0, 0, 0);
      }
      __builtin_amdgcn_s_setprio(0);
    }

    if (t == ntiles - 1) {            // diagonal tile: mask key > query
      const int qrel = w * 16 + li;
      #pragma unroll
      for (int n = 0; n < 4; ++n)
        #pragma unroll
        for (int r = 0; r < 4; ++r)
          if (n * 16 + lg * 4 + r > qrel) sc[n][r] = -1e9f;
    }

    // no-max softmax: P = exp2(S - 8), accumulate l; pack to bf16 for PV
    float psum = 0.f;
    #pragma unroll
    for (int n = 0; n < 4; ++n) {
      float p0 = exp2f(sc[n][0] - 8.0f);
      float p1 = exp2f(sc[n][1] - 8.0f);
      float p2 = exp2f(sc[n][2] - 8.0f);
      float p3 = exp2f(sc[n][3] - 8.0f);
      psum += (p0 + p1) + (p2 + p3);
      // fast bf16 pair-pack: +0x8000 round bias, v_perm selects hi16 halves
      unsigned a0 = __float_as_uint(p0) + 0x8000u;
      unsigned a1 = __float_as_uint(p1) + 0x8000u;
      unsigned a2 = __float_as_uint(p2) + 0x8000u;
      unsigned a3 = __float_as_uint(p3) + 0x8000u;
      uint2 wv;
      wv.x = __builtin_amdgcn_perm(a1, a0, 0x07060302u);  // hi16(a1)<<16 | hi16(a0)
      wv.y = __builtin_amdgcn_perm(a3, a2, 0x07060302u);
      *(uint2*)(&Ps[w][li * LDK + n * 16 + lg * 4]) = wv;
    }
    psum += __shfl_xor(psum, 16);
    psum += __shfl_xor(psum, 32);
    lrow += psum;

    // O += P @ V ; V fragments straight from L2 (Vt is [d][s])
    {
      s16x8 vf0[4], vf1[4];
      #pragma unroll
      for (int n = 0; n < 4; ++n) {
        const u16* vp = vptr + (size_t)(n * 16) * HS + kv0;
        vf0[n] = *(const s16x8*)(vp);
        vf1[n] = *(const s16x8*)(vp + 32);
      }
      s16x8 pf0 = *(const s16x8*)(&Ps[w][li * LDK + lg * 8]);
      s16x8 pf1 = *(const s16x8*)(&Ps[w][li * LDK + 32 + lg * 8]);
      __builtin_amdgcn_s_setprio(1);
      #pragma unroll
      for (int n = 0; n < 4; ++n) {
        o[n] = __builtin_amdgcn_mfma_f32_16x16x32_bf16(pf0, vf0[n], o[n], 0, 0, 0);
        o[n] = __builtin_amdgcn_mfma_f32_16x16x32_bf16(pf1, vf1[n], o[n], 0, 0, 0);
      }
      __builtin_amdgcn_s_setprio(0);
    }
  }

  // epilogue: attn[b][s][h*64+d] bf16 ; o row = q(lg*4+r), col = d(n*16+li)
  float linv = 1.0f / lrow;
  float linvq[4];
  #pragma unroll
  for (int r = 0; r < 4; ++r) linvq[r] = __shfl(linv, lg * 4 + r);
  #pragma unroll
  for (int n = 0; n < 4; ++n)
    #pragma unroll
    for (int r = 0; r < 4; ++r) {
      int srow = q0 + w * 16 + lg * 4 + r;
      attnOut[(size_t)(b * HS + srow) * HIDN + h * 64 + n * 16 + li] = f2bf(o[n][r] * linvq[r]);
    }
}

// ---------------- K3: output GEMM attn @ Wo -> fp32 d_out -------------------
__global__ __launch_bounds__(256) void k_out(const u16* __restrict__ A, const u16* __restrict__ Bt,
                                             float* __restrict__ out) {
  __shared__ __align__(16) u16 As[BM * 64];
  __shared__ __align__(16) u16 Bs[BN * 64];
  const int tid = threadIdx.x;
  const int lane = tid & 63, wave = tid >> 6;
  const int wr = wave >> 1, wc = wave & 1;
  const int lg = lane >> 4, li = lane & 15;
  const int bm0 = blockIdx.y * BM, bn0 = blockIdx.x * BN;

  const int srow = lane >> 3;
  const int scol = (lane & 7) * 8;

  f32x4 acc[4][4];
  #pragma unroll
  for (int m = 0; m < 4; ++m)
    #pragma unroll
    for (int n = 0; n < 4; ++n) acc[m][n] = (f32x4){0.f, 0.f, 0.f, 0.f};

  for (int k0 = 0; k0 < HIDN; k0 += BK) {
    __syncthreads();
    #pragma unroll
    for (int c = 0; c < 4; ++c) {
      const int ci = wave * 4 + c;
      const int row = ci * 8 + srow;
      gload16(A  + (size_t)(bm0 + row) * HIDN + k0 + scol, &As[ci * 512]);
      gload16(Bt + (size_t)(bn0 + row) * HIDN + k0 + scol, &Bs[ci * 512]);
    }
    __syncthreads();
    #pragma unroll
    for (int kk = 0; kk < 2; ++kk) {
      s16x8 af[4], bfr[4];
      #pragma unroll
      for (int m = 0; m < 4; ++m) af[m]  = *(const s16x8*)(&As[(wr * 64 + m * 16 + li) * 64 + kk * 32 + lg * 8]);
      #pragma unroll
      for (int n = 0; n < 4; ++n) bfr[n] = *(const s16x8*)(&Bs[(wc * 64 + n * 16 + li) * 64 + kk * 32 + lg * 8]);
      __builtin_amdgcn_s_setprio(1);
      #pragma unroll
      for (int m = 0; m < 4; ++m)
        #pragma unroll
        for (int n = 0; n < 4; ++n)
          acc[m][n] = __builtin_amdgcn_mfma_f32_16x16x32_bf16(af[m], bfr[n], acc[m][n], 0, 0, 0);
      __builtin_amdgcn_s_setprio(0);
    }
  }

  #pragma unroll
  for (int m = 0; m < 4; ++m)
    #pragma unroll
    for (int r = 0; r < 4; ++r) {
      int t = bm0 + wr * 64 + m * 16 + lg * 4 + r;
      #pragma unroll
      for (int n = 0; n < 4; ++n) {
        int c = bn0 + wc * 64 + n * 16 + li;
        out[(size_t)t * HIDN + c] = acc[m][n][r];
      }
    }
}

extern "C" void kernel_launch(void* const* d_in, const int* in_sizes, int n_in,
                              void* d_out, int out_size, void* d_ws, size_t ws_size,
                              hipStream_t stream) {
  const float* hs   = (const float*)d_in[0];
  const float* info = (const float*)d_in[1];
  const float* Wq   = (const float*)d_in[2];
  const float* Wk   = (const float*)d_in[3];
  const float* Wv   = (const float*)d_in[4];
  const float* Wo   = (const float*)d_in[5];
  float* out = (float*)d_out;

  char* ws = (char*)d_ws;
  u16* Xbf  = (u16*)(ws);                         // 8 MB, reused as attn buffer after K1
  u16* Wt   = (u16*)(ws + ((size_t)8  << 20));    // 8 MB: Wq^T,Wk^T,Wv^T,Wo^T bf16
  u16* Qb   = (u16*)(ws + ((size_t)16 << 20));    // 8 MB [B][H][S][D]
  u16* Kb   = (u16*)(ws + ((size_t)24 << 20));    // 8 MB [B][H][S][D]
  u16* Vt   = (u16*)(ws + ((size_t)32 << 20));    // 8 MB [B][H][D][S]
  u16* attn = Xbf;                                 // [4096][1024] bf16

  k_cvt<<<(MROWS * HIDN / 4 + 255) / 256, 256, 0, stream>>>(hs, Xbf, MROWS * HIDN);
  k_transpose<<<dim3(16, 16, 4), 256, 0, stream>>>(Wq, Wk, Wv, Wo, Wt);
  k_qkv<<<dim3(HIDN / BN, MROWS / BM, 3), 256, 0, stream>>>(Xbf, Wt, info, Qb, Kb, Vt);
  k_attn<<<dim3(1024), 256, 0, stream>>>(Qb, Kb, Vt, attn);
  k_out<<<dim3(HIDN / BN, MROWS / BM), 256, 0, stream>>>(attn, Wt + (size_t)3 * HIDN * HIDN, out);
}

// Round 9
// 118.477 us; speedup vs baseline: 1.8623x; 1.8623x over previous
//
#include <hip/hip_runtime.h>
#include <hip/hip_bf16.h>

// Problem constants
#define HB 2
#define HS 2048
#define HH 16
#define HD 64
#define HIDN 1024
#define MROWS 4096   // B*S

typedef __attribute__((ext_vector_type(8))) short s16x8;   // 8 bf16 (4 VGPRs)
typedef __attribute__((ext_vector_type(4))) float f32x4;   // MFMA accumulator
typedef unsigned short u16;

__device__ inline u16 f2bf(float f) {
  union { __hip_bfloat16 h; u16 u; } cvt;
  cvt.h = __float2bfloat16(f);
  return cvt.u;
}

// async global->LDS DMA, 16B per lane. lds base must be wave-uniform;
// lane i lands at base + i*16B. global addr is per-lane.
__device__ __forceinline__ void gload16(const u16* g, u16* l) {
  __builtin_amdgcn_global_load_lds((const __attribute__((address_space(1))) void*)g,
                                   (__attribute__((address_space(3))) void*)l, 16, 0, 0);
}

// ---------------- K0a: fp32 -> bf16 convert (hidden_states) ----------------
__global__ __launch_bounds__(256) void k_cvt(const float* __restrict__ in, u16* __restrict__ out, int n) {
  int i = (blockIdx.x * 256 + threadIdx.x) * 4;
  if (i >= n) return;
  float4 a = *(const float4*)(in + i);
  ushort4 r;
  r.x = f2bf(a.x); r.y = f2bf(a.y); r.z = f2bf(a.z); r.w = f2bf(a.w);
  *(ushort4*)(out + i) = r;
}

// ---------------- K0b: weight transpose fp32[K][C] -> bf16[C][K] -----------
__global__ __launch_bounds__(256) void k_transpose(const float* __restrict__ W0, const float* __restrict__ W1,
                                                   const float* __restrict__ W2, const float* __restrict__ W3,
                                                   u16* __restrict__ out) {
  const float* W = (blockIdx.z == 0) ? W0 : (blockIdx.z == 1) ? W1 : (blockIdx.z == 2) ? W2 : W3;
  u16* O = out + (size_t)blockIdx.z * HIDN * HIDN;
  __shared__ float tile[64][65];
  int k0 = blockIdx.y * 64, c0 = blockIdx.x * 64;
  #pragma unroll
  for (int i = 0; i < 16; ++i) {
    int id = threadIdx.x + i * 256;
    int r = id >> 6, c = id & 63;
    tile[r][c] = W[(size_t)(k0 + r) * HIDN + c0 + c];
  }
  __syncthreads();
  #pragma unroll
  for (int i = 0; i < 16; ++i) {
    int id = threadIdx.x + i * 256;
    int r = id >> 6, c = id & 63;
    O[(size_t)(c0 + r) * HIDN + k0 + c] = f2bf(tile[c][r]);
  }
}

// ---------------- K1: QKV GEMM + info add + RoPE epilogue -------------------
// XCD-aware 1-D grid (768 blocks): XCD g owns m-tiles 4g..4g+3 (A-panels stay
// L2-resident, 1MB/XCD); n fastest (B-panel 2MB/z L2-resident); z outermost.
#define BM 128
#define BN 128
#define BK 64
#define LDK 72   // padded stride for k_attn LDS tiles (16B-aligned rows)

__global__ __launch_bounds__(256) void k_qkv(const u16* __restrict__ X, const u16* __restrict__ Wt,
                                             const float* __restrict__ info,
                                             u16* __restrict__ Qb, u16* __restrict__ Kb, u16* __restrict__ Vt) {
  __shared__ __align__(16) u16 smem[128 * 136];
  const int bid = blockIdx.x;
  const int g   = bid & 7;          // XCD (bid%8 round-robin)
  const int idx = bid >> 3;         // 0..95
  const int nt  = idx & 7;          // n-tile, fastest
  const int ml  = (idx >> 3) & 3;   // m-local
  const int z   = idx >> 5;         // 0..2
  const int mt  = g * 4 + ml;       // m-tile 0..31
  const u16* Bt = Wt + (size_t)z * HIDN * HIDN;
  const int tid = threadIdx.x;
  const int lane = tid & 63, wave = tid >> 6;
  const int wr = wave >> 1, wc = wave & 1;     // 2x2 waves, each owns 64x64
  const int lg = lane >> 4, li = lane & 15;
  const int bm0 = mt * BM, bn0 = nt * BN;

  const int srow = lane >> 3;          // 0..7 row within 1KB chunk
  const int scol = (lane & 7) * 8;     // k-col element within row

  f32x4 acc[4][4];
  #pragma unroll
  for (int m = 0; m < 4; ++m)
    #pragma unroll
    for (int n = 0; n < 4; ++n) acc[m][n] = (f32x4){0.f, 0.f, 0.f, 0.f};

  for (int k0 = 0; k0 < HIDN; k0 += BK) {
    __syncthreads();
    #pragma unroll
    for (int c = 0; c < 4; ++c) {
      const int ci = wave * 4 + c;
      const int row = ci * 8 + srow;
      gload16(X  + (size_t)(bm0 + row) * HIDN + k0 + scol, &smem[ci * 512]);
      gload16(Bt + (size_t)(bn0 + row) * HIDN + k0 + scol, &smem[8192 + ci * 512]);
    }
    __syncthreads();
    #pragma unroll
    for (int kk = 0; kk < 2; ++kk) {
      s16x8 af[4], bfr[4];
      #pragma unroll
      for (int m = 0; m < 4; ++m) af[m]  = *(const s16x8*)(&smem[(wr * 64 + m * 16 + li) * 64 + kk * 32 + lg * 8]);
      #pragma unroll
      for (int n = 0; n < 4; ++n) bfr[n] = *(const s16x8*)(&smem[8192 + (wc * 64 + n * 16 + li) * 64 + kk * 32 + lg * 8]);
      __builtin_amdgcn_s_setprio(1);
      #pragma unroll
      for (int m = 0; m < 4; ++m)
        #pragma unroll
        for (int n = 0; n < 4; ++n)
          acc[m][n] = __builtin_amdgcn_mfma_f32_16x16x32_bf16(af[m], bfr[n], acc[m][n], 0, 0, 0);
      __builtin_amdgcn_s_setprio(0);
    }
  }

  if (z < 2) {
    u16* dst = (z == 0) ? Qb : Kb;
    #pragma unroll
    for (int m = 0; m < 4; ++m) {
      #pragma unroll
      for (int r = 0; r < 4; ++r) {
        int t = bm0 + wr * 64 + m * 16 + lg * 4 + r;   // global token row
        int b = t >> 11, s = t & (HS - 1);
        #pragma unroll
        for (int n = 0; n < 2; ++n) {                  // rope pairs: frag n with frag n+2
          int c1 = bn0 + wc * 64 + n * 16 + li;        // col for d1 < 32
          float v1 = acc[m][n][r]     + info[(size_t)t * HIDN + c1];
          float v2 = acc[m][n + 2][r] + info[(size_t)t * HIDN + c1 + 32];
          int j = n * 16 + li;                          // freq index 0..31
          float invf = exp2f(-0.41524101186092030f * (float)j);  // 10000^(-j/32)
          float ang = (float)s * invf;
          float sn, cs;
          __sincosf(ang, &sn, &cs);
          float o1 = v1 * cs - v2 * sn;
          float o2 = v2 * cs + v1 * sn;
          if (z == 0) { o1 *= 0.18033688011f; o2 *= 0.18033688011f; } // 1/8 * log2(e)
          int h = c1 >> 6, d1 = c1 & 63;
          size_t base = ((size_t)(b * HH + h) * HS + s) * HD;
          dst[base + d1]      = f2bf(o1);
          dst[base + d1 + 32] = f2bf(o2);
        }
      }
    }
  } else {
    // V: transpose 128x128 block via LDS, then coalesced 16B stores to [B][H][D][S]
    __syncthreads();
    #pragma unroll
    for (int m = 0; m < 4; ++m)
      #pragma unroll
      for (int n = 0; n < 4; ++n)
        #pragma unroll
        for (int r = 0; r < 4; ++r) {
          int cl = wc * 64 + n * 16 + li;
          int ml2 = wr * 64 + m * 16 + lg * 4 + r;
          smem[cl * 136 + ml2] = f2bf(acc[m][n][r]);
        }
    __syncthreads();
    const int b = bm0 >> 11, s0 = bm0 & (HS - 1);
    #pragma unroll
    for (int p = 0; p < 8; ++p) {
      int id = tid + p * 256;
      int cl = id >> 4, m8 = (id & 15) * 8;
      int c = bn0 + cl;
      int h = c >> 6, d = c & 63;
      s16x8 v = *(const s16x8*)(&smem[cl * 136 + m8]);
      *(s16x8*)(&Vt[((size_t)(b * HH + h) * HD + d) * HS + s0 + m8]) = v;
    }
  }
}

// ---------------- K2: causal flash attention (4-wave, dbuf, no-max softmax) -
// grid 1024: bh = bidx&31, j = 31 - (bidx>>5) -> largest-work blocks first,
// rest backfill. Block = 4 waves x 16 q-rows at q0=j*64; ntiles = j+1.
// Scores in exp2 domain, |S| bounded: P = exp2(S-8), no running max/rescale.
// K/V double-buffered, one barrier per tile. (R6-verified: 51.6us)
__global__ __launch_bounds__(256, 3) void k_attn(const u16* __restrict__ Qb, const u16* __restrict__ Kb,
                                                 const u16* __restrict__ Vt, u16* __restrict__ attnOut) {
  __shared__ u16 Ks[2][64 * LDK];
  __shared__ u16 Vs[2][64 * LDK];   // V^T tile: [d][key]
  __shared__ u16 Ps[4][16 * LDK];   // per-wave P tile: [qrow][key]
  const int bidx = blockIdx.x;
  const int bh = bidx & 31;
  const int j  = 31 - (bidx >> 5);
  const int q0 = j * 64;
  const int ntiles = j + 1;

  const u16* Qh = Qb + (size_t)bh * HS * HD;
  const u16* Kh = Kb + (size_t)bh * HS * HD;
  const u16* Vh = Vt + (size_t)bh * HD * HS;
  const int tid = threadIdx.x;
  const int lane = tid & 63, w = tid >> 6;
  const int lg = lane >> 4, li = lane & 15;
  const int b = bh >> 4, h = bh & 15;

  const int row16 = tid >> 3;        // 0..31 (pass 2: +32)
  const int col8  = (tid & 7) * 8;   // 0..56

  // Q fragments in registers (Q pre-scaled by 0.125*log2e)
  s16x8 qf[2];
  #pragma unroll
  for (int kk = 0; kk < 2; ++kk)
    qf[kk] = *(const s16x8*)(Qh + (size_t)(q0 + w * 16 + li) * HD + kk * 32 + lg * 8);

  f32x4 o[4];
  #pragma unroll
  for (int n = 0; n < 4; ++n) o[n] = (f32x4){0.f, 0.f, 0.f, 0.f};
  float lrow = 0.f;

  // prologue: stage tile 0 into buf 0
  {
    uint4 ka = *(const uint4*)(Kh + (size_t)row16 * HD + col8);
    uint4 kb = *(const uint4*)(Kh + (size_t)(row16 + 32) * HD + col8);
    uint4 va = *(const uint4*)(Vh + (size_t)row16 * HS + col8);
    uint4 vb = *(const uint4*)(Vh + (size_t)(row16 + 32) * HS + col8);
    *(uint4*)(&Ks[0][row16 * LDK + col8])        = ka;
    *(uint4*)(&Ks[0][(row16 + 32) * LDK + col8]) = kb;
    *(uint4*)(&Vs[0][row16 * LDK + col8])        = va;
    *(uint4*)(&Vs[0][(row16 + 32) * LDK + col8]) = vb;
  }
  __syncthreads();

  for (int t = 0; t < ntiles; ++t) {
    const int cur = t & 1;
    uint4 rKa, rKb, rVa, rVb;
    const bool more = (t + 1 < ntiles);
    if (more) {                       // issue next-tile loads early (hide latency)
      const int kv1 = (t + 1) * 64;
      rKa = *(const uint4*)(Kh + (size_t)(kv1 + row16) * HD + col8);
      rKb = *(const uint4*)(Kh + (size_t)(kv1 + row16 + 32) * HD + col8);
      rVa = *(const uint4*)(Vh + (size_t)row16 * HS + kv1 + col8);
      rVb = *(const uint4*)(Vh + (size_t)(row16 + 32) * HS + kv1 + col8);
    }

    // S^T = K @ Q^T : lane li owns q-row (q0+w*16+li), keys n*16+lg*4+r
    f32x4 sc[4];
    #pragma unroll
    for (int n = 0; n < 4; ++n) sc[n] = (f32x4){0.f, 0.f, 0.f, 0.f};
    __builtin_amdgcn_s_setprio(1);
    #pragma unroll
    for (int kk = 0; kk < 2; ++kk) {
      #pragma unroll
      for (int n = 0; n < 4; ++n) {
        s16x8 kfr = *(const s16x8*)(&Ks[cur][(n * 16 + li) * LDK + kk * 32 + lg * 8]);
        sc[n] = __builtin_amdgcn_mfma_f32_16x16x32_bf16(kfr, qf[kk], sc[n], 0, 0, 0);
      }
    }
    __builtin_amdgcn_s_setprio(0);

    if (t == ntiles - 1) {            // diagonal tile: mask key > query
      const int qrel = w * 16 + li;
      #pragma unroll
      for (int n = 0; n < 4; ++n)
        #pragma unroll
        for (int r = 0; r < 4; ++r)
          if (n * 16 + lg * 4 + r > qrel) sc[n][r] = -1e9f;
    }

    // no-max softmax: P = exp2(S - 8), accumulate l; pack to bf16 for PV
    float psum = 0.f;
    #pragma unroll
    for (int n = 0; n < 4; ++n) {
      float p0 = exp2f(sc[n][0] - 8.0f);
      float p1 = exp2f(sc[n][1] - 8.0f);
      float p2 = exp2f(sc[n][2] - 8.0f);
      float p3 = exp2f(sc[n][3] - 8.0f);
      psum += (p0 + p1) + (p2 + p3);
      // fast bf16 pair-pack: +0x8000 round bias, v_perm selects hi16 halves
      unsigned a0 = __float_as_uint(p0) + 0x8000u;
      unsigned a1 = __float_as_uint(p1) + 0x8000u;
      unsigned a2 = __float_as_uint(p2) + 0x8000u;
      unsigned a3 = __float_as_uint(p3) + 0x8000u;
      uint2 wv;
      wv.x = __builtin_amdgcn_perm(a1, a0, 0x07060302u);  // hi16(a1)<<16 | hi16(a0)
      wv.y = __builtin_amdgcn_perm(a3, a2, 0x07060302u);
      *(uint2*)(&Ps[w][li * LDK + n * 16 + lg * 4]) = wv;
    }
    psum += __shfl_xor(psum, 16);
    psum += __shfl_xor(psum, 32);
    lrow += psum;

    // O += P @ V
    __builtin_amdgcn_s_setprio(1);
    #pragma unroll
    for (int kk = 0; kk < 2; ++kk) {
      s16x8 pf = *(const s16x8*)(&Ps[w][li * LDK + kk * 32 + lg * 8]);
      #pragma unroll
      for (int n = 0; n < 4; ++n) {
        s16x8 vf = *(const s16x8*)(&Vs[cur][(n * 16 + li) * LDK + kk * 32 + lg * 8]);
        o[n] = __builtin_amdgcn_mfma_f32_16x16x32_bf16(pf, vf, o[n], 0, 0, 0);
      }
    }
    __builtin_amdgcn_s_setprio(0);

    if (more) {                       // write next tile into other buffer
      *(uint4*)(&Ks[cur ^ 1][row16 * LDK + col8])        = rKa;
      *(uint4*)(&Ks[cur ^ 1][(row16 + 32) * LDK + col8]) = rKb;
      *(uint4*)(&Vs[cur ^ 1][row16 * LDK + col8])        = rVa;
      *(uint4*)(&Vs[cur ^ 1][(row16 + 32) * LDK + col8]) = rVb;
      __syncthreads();
    }
  }

  // epilogue: attn[b][s][h*64+d] bf16 ; o row = q(lg*4+r), col = d(n*16+li)
  float linv = 1.0f / lrow;
  float linvq[4];
  #pragma unroll
  for (int r = 0; r < 4; ++r) linvq[r] = __shfl(linv, lg * 4 + r);
  #pragma unroll
  for (int n = 0; n < 4; ++n)
    #pragma unroll
    for (int r = 0; r < 4; ++r) {
      int srow = q0 + w * 16 + lg * 4 + r;
      attnOut[(size_t)(b * HS + srow) * HIDN + h * 64 + n * 16 + li] = f2bf(o[n][r] * linvq[r]);
    }
}

// ---------------- K3: output GEMM attn @ Wo -> fp32 d_out -------------------
// XCD-aware 1-D grid (256 blocks): XCD g owns m-tiles 4g..4g+3; n fastest.
__global__ __launch_bounds__(256) void k_out(const u16* __restrict__ A, const u16* __restrict__ Bt,
                                             float* __restrict__ out) {
  __shared__ __align__(16) u16 As[BM * 64];
  __shared__ __align__(16) u16 Bs[BN * 64];
  const int bid = blockIdx.x;
  const int g   = bid & 7;
  const int idx = bid >> 3;         // 0..31
  const int nt  = idx & 7;
  const int ml  = idx >> 3;         // 0..3
  const int mt  = g * 4 + ml;
  const int tid = threadIdx.x;
  const int lane = tid & 63, wave = tid >> 6;
  const int wr = wave >> 1, wc = wave & 1;
  const int lg = lane >> 4, li = lane & 15;
  const int bm0 = mt * BM, bn0 = nt * BN;

  const int srow = lane >> 3;
  const int scol = (lane & 7) * 8;

  f32x4 acc[4][4];
  #pragma unroll
  for (int m = 0; m < 4; ++m)
    #pragma unroll
    for (int n = 0; n < 4; ++n) acc[m][n] = (f32x4){0.f, 0.f, 0.f, 0.f};

  for (int k0 = 0; k0 < HIDN; k0 += BK) {
    __syncthreads();
    #pragma unroll
    for (int c = 0; c < 4; ++c) {
      const int ci = wave * 4 + c;
      const int row = ci * 8 + srow;
      gload16(A  + (size_t)(bm0 + row) * HIDN + k0 + scol, &As[ci * 512]);
      gload16(Bt + (size_t)(bn0 + row) * HIDN + k0 + scol, &Bs[ci * 512]);
    }
    __syncthreads();
    #pragma unroll
    for (int kk = 0; kk < 2; ++kk) {
      s16x8 af[4], bfr[4];
      #pragma unroll
      for (int m = 0; m < 4; ++m) af[m]  = *(const s16x8*)(&As[(wr * 64 + m * 16 + li) * 64 + kk * 32 + lg * 8]);
      #pragma unroll
      for (int n = 0; n < 4; ++n) bfr[n] = *(const s16x8*)(&Bs[(wc * 64 + n * 16 + li) * 64 + kk * 32 + lg * 8]);
      __builtin_amdgcn_s_setprio(1);
      #pragma unroll
      for (int m = 0; m < 4; ++m)
        #pragma unroll
        for (int n = 0; n < 4; ++n)
          acc[m][n] = __builtin_amdgcn_mfma_f32_16x16x32_bf16(af[m], bfr[n], acc[m][n], 0, 0, 0);
      __builtin_amdgcn_s_setprio(0);
    }
  }

  #pragma unroll
  for (int m = 0; m < 4; ++m)
    #pragma unroll
    for (int r = 0; r < 4; ++r) {
      int t = bm0 + wr * 64 + m * 16 + lg * 4 + r;
      #pragma unroll
      for (int n = 0; n < 4; ++n) {
        int c = bn0 + wc * 64 + n * 16 + li;
        out[(size_t)t * HIDN + c] = acc[m][n][r];
      }
    }
}

extern "C" void kernel_launch(void* const* d_in, const int* in_sizes, int n_in,
                              void* d_out, int out_size, void* d_ws, size_t ws_size,
                              hipStream_t stream) {
  const float* hs   = (const float*)d_in[0];
  const float* info = (const float*)d_in[1];
  const float* Wq   = (const float*)d_in[2];
  const float* Wk   = (const float*)d_in[3];
  const float* Wv   = (const float*)d_in[4];
  const float* Wo   = (const float*)d_in[5];
  float* out = (float*)d_out;

  char* ws = (char*)d_ws;
  u16* Xbf  = (u16*)(ws);                         // 8 MB, reused as attn buffer after K1
  u16* Wt   = (u16*)(ws + ((size_t)8  << 20));    // 8 MB: Wq^T,Wk^T,Wv^T,Wo^T bf16
  u16* Qb   = (u16*)(ws + ((size_t)16 << 20));    // 8 MB [B][H][S][D]
  u16* Kb   = (u16*)(ws + ((size_t)24 << 20));    // 8 MB [B][H][S][D]
  u16* Vt   = (u16*)(ws + ((size_t)32 << 20));    // 8 MB [B][H][D][S]
  u16* attn = Xbf;                                 // [4096][1024] bf16

  k_cvt<<<(MROWS * HIDN / 4 + 255) / 256, 256, 0, stream>>>(hs, Xbf, MROWS * HIDN);
  k_transpose<<<dim3(16, 16, 4), 256, 0, stream>>>(Wq, Wk, Wv, Wo, Wt);
  k_qkv<<<dim3(768), 256, 0, stream>>>(Xbf, Wt, info, Qb, Kb, Vt);
  k_attn<<<dim3(1024), 256, 0, stream>>>(Qb, Kb, Vt, attn);
  k_out<<<dim3(256), 256, 0, stream>>>(attn, Wt + (size_t)3 * HIDN * HIDN, out);
}